// Round 1
// baseline (2729.865 us; speedup 1.0000x reference)
//
#include <hip/hip_runtime.h>
#include <cstdio>
#include <cstdint>

// Problem constants
#define B_  16
#define T_  4096
#define D_  512
#define U_  512
#define KK  1024            // W*D
#define M_  (B_*T_)         // 65536 rows

// GEMM tiling
#define BM 128
#define BN 128
#define BK 16

// Scan chunking
#define CHUNK 128
#define NCH   (T_/CHUNK)    // 32 chunks per sequence

// ---------------------------------------------------------------------------
// GEMM + bias + activation. Computes, for gate g in {z,f,o}:
//   y[m,u] = sum_k A[m,k] * Wg[k,u] + bg[u],  A[m,k] = x[(m-1)*512 + k]
//            (zero when t==0 && k<512; rows never cross batch since only t-1)
// gate 0 -> tanh -> zbuf ; gate 1 -> sigmoid -> fbuf ; gate 2 -> sigmoid -> obuf
// grid: (M_/BM, 12) ; 12 = 3 gates * (U_/BN)
// ---------------------------------------------------------------------------
__global__ __launch_bounds__(256)
void gemm_act_kernel(const float* __restrict__ x,
                     const float* __restrict__ Wz, const float* __restrict__ bz,
                     const float* __restrict__ Wf, const float* __restrict__ bf,
                     const float* __restrict__ Wo, const float* __restrict__ bo,
                     float* __restrict__ zbuf, float* __restrict__ fbuf,
                     float* __restrict__ obuf)
{
    __shared__ float As[BK][BM + 4];   // +4 pad: avoid row-stride pow2
    __shared__ float Bs[BK][BN];

    const int m0   = blockIdx.x * BM;
    const int nb   = blockIdx.y;       // 0..11
    const int gate = nb >> 2;          // 0:z 1:f 2:o
    const int u0   = (nb & 3) * BN;

    const float* __restrict__ Wg   = (gate == 0) ? Wz : (gate == 1 ? Wf : Wo);
    const float* __restrict__ bg   = (gate == 0) ? bz : (gate == 1 ? bf : bo);
    float*       __restrict__ outg = (gate == 0) ? zbuf : (gate == 1 ? fbuf : obuf);

    const int tid = threadIdx.x;
    const int tx  = tid & 15;          // micro-tile n index (0..15)
    const int ty  = tid >> 4;          // micro-tile m index (0..15)

    float acc[8][8];
    #pragma unroll
    for (int i = 0; i < 8; ++i)
        #pragma unroll
        for (int j = 0; j < 8; ++j)
            acc[i][j] = 0.0f;

    // A staging: thread loads one float4 along k for rows a_r and a_r+64
    const int a_k4 = (tid & 3) * 4;    // k offset within tile: 0,4,8,12
    const int a_r  = tid >> 2;         // row 0..63
    // B staging: thread loads one float4 along u for k rows b_k and b_k+8
    const int b_u4 = (tid & 31) * 4;   // u offset within tile
    const int b_k  = tid >> 5;         // 0..7

    for (int k0 = 0; k0 < KK; k0 += BK) {
        // ---- stage A tile (128 rows x 16 k) ----
        #pragma unroll
        for (int h = 0; h < 2; ++h) {
            const int r = a_r + h * 64;
            const int m = m0 + r;
            const int t = m & (T_ - 1);
            const int k = k0 + a_k4;
            float4 v = make_float4(0.f, 0.f, 0.f, 0.f);
            if (!(t == 0 && k < 512)) {
                v = *reinterpret_cast<const float4*>(x + (long long)(m - 1) * D_ + k);
            }
            As[a_k4 + 0][r] = v.x;
            As[a_k4 + 1][r] = v.y;
            As[a_k4 + 2][r] = v.z;
            As[a_k4 + 3][r] = v.w;
        }
        // ---- stage B tile (16 k x 128 u) ----
        #pragma unroll
        for (int h = 0; h < 2; ++h) {
            const int kk = b_k + h * 8;
            const float4 v = *reinterpret_cast<const float4*>(
                Wg + (long long)(k0 + kk) * U_ + u0 + b_u4);
            *reinterpret_cast<float4*>(&Bs[kk][b_u4]) = v;
        }
        __syncthreads();

        // ---- 8x8 micro-kernel over BK ----
        #pragma unroll
        for (int kk = 0; kk < BK; ++kk) {
            float a[8], bb[8];
            #pragma unroll
            for (int i = 0; i < 8; ++i) a[i] = As[kk][ty * 8 + i];
            #pragma unroll
            for (int j = 0; j < 8; ++j) bb[j] = Bs[kk][tx * 8 + j];
            #pragma unroll
            for (int i = 0; i < 8; ++i)
                #pragma unroll
                for (int j = 0; j < 8; ++j)
                    acc[i][j] = fmaf(a[i], bb[j], acc[i][j]);
        }
        __syncthreads();
    }

    // ---- epilogue: bias + activation + store ----
    float biasv[8];
    #pragma unroll
    for (int j = 0; j < 8; ++j) biasv[j] = bg[u0 + tx * 8 + j];

    #pragma unroll
    for (int i = 0; i < 8; ++i) {
        const int m = m0 + ty * 8 + i;
        float res[8];
        #pragma unroll
        for (int j = 0; j < 8; ++j) {
            const float v = acc[i][j] + biasv[j];
            res[j] = (gate == 0) ? tanhf(v) : (1.0f / (1.0f + expf(-v)));
        }
        float4* p = reinterpret_cast<float4*>(outg + (long long)m * U_ + u0 + tx * 8);
        p[0] = make_float4(res[0], res[1], res[2], res[3]);
        p[1] = make_float4(res[4], res[5], res[6], res[7]);
    }
}

// ---------------------------------------------------------------------------
// Phase 1: per-chunk affine summary.  h -> A*h + B composed over CHUNK steps.
// grid: B_*NCH*2 blocks of 256 (two blocks cover U=512)
// ---------------------------------------------------------------------------
__global__ __launch_bounds__(256)
void chunk_summary_kernel(const float* __restrict__ fbuf,
                          const float* __restrict__ zbuf,
                          float* __restrict__ Ach, float* __restrict__ Bch)
{
    const int blk   = blockIdx.x;
    const int uhalf = blk & 1;
    const int bc    = blk >> 1;          // 0..B_*NCH-1
    const int c     = bc & (NCH - 1);
    const int b     = bc >> 5;           // NCH = 32
    const int u     = uhalf * 256 + threadIdx.x;

    const long long base = ((long long)(b * T_ + c * CHUNK)) * U_ + u;
    float A = 1.0f, Bv = 0.0f;
    #pragma unroll 4
    for (int i = 0; i < CHUNK; ++i) {
        const float f = fbuf[base + (long long)i * U_];
        const float z = zbuf[base + (long long)i * U_];
        Bv = f * Bv + (1.0f - f) * z;
        A *= f;
    }
    const int idx = (b * NCH + c) * U_ + u;
    Ach[idx] = A;
    Bch[idx] = Bv;
}

// ---------------------------------------------------------------------------
// Phase 2: exclusive prefix over chunks per (b,u). 8192 threads total.
// ---------------------------------------------------------------------------
__global__ __launch_bounds__(256)
void chunk_prefix_kernel(const float* __restrict__ Ach,
                         const float* __restrict__ Bch,
                         float* __restrict__ Hin)
{
    const int g = blockIdx.x * 256 + threadIdx.x;   // 0..8191
    const int b = g >> 9;
    const int u = g & (U_ - 1);
    float h = 0.0f;
    #pragma unroll 4
    for (int c = 0; c < NCH; ++c) {
        const int idx = (b * NCH + c) * U_ + u;
        Hin[idx] = h;
        h = Ach[idx] * h + Bch[idx];
    }
}

// ---------------------------------------------------------------------------
// Phase 3: apply scan within chunk, multiply by o, write output.
// ---------------------------------------------------------------------------
__global__ __launch_bounds__(256)
void scan_apply_kernel(const float* __restrict__ fbuf,
                       const float* __restrict__ zbuf,
                       const float* __restrict__ obuf,
                       const float* __restrict__ Hin,
                       float* __restrict__ out)
{
    const int blk   = blockIdx.x;
    const int uhalf = blk & 1;
    const int bc    = blk >> 1;
    const int c     = bc & (NCH - 1);
    const int b     = bc >> 5;
    const int u     = uhalf * 256 + threadIdx.x;

    const long long base = ((long long)(b * T_ + c * CHUNK)) * U_ + u;
    float h = Hin[(b * NCH + c) * U_ + u];
    #pragma unroll 4
    for (int i = 0; i < CHUNK; ++i) {
        const long long p = base + (long long)i * U_;
        const float f = fbuf[p];
        const float z = zbuf[p];
        const float o = obuf[p];
        h = f * h + (1.0f - f) * z;
        out[p] = o * h;
    }
}

// ---------------------------------------------------------------------------
extern "C" void kernel_launch(void* const* d_in, const int* in_sizes, int n_in,
                              void* d_out, int out_size, void* d_ws, size_t ws_size,
                              hipStream_t stream)
{
    const float* x  = (const float*)d_in[0];
    const float* Wz = (const float*)d_in[1];
    const float* bz = (const float*)d_in[2];
    const float* Wf = (const float*)d_in[3];
    const float* bf = (const float*)d_in[4];
    const float* Wo = (const float*)d_in[5];
    const float* bo = (const float*)d_in[6];
    float* out = (float*)d_out;

    const size_t S  = (size_t)M_ * U_;           // 33,554,432 elems per buffer
    const size_t Sc = (size_t)B_ * NCH * U_;     // 262,144 elems per chunk buf
    float* zbuf = (float*)d_ws;
    float* fbuf = zbuf + S;
    float* obuf = fbuf + S;
    float* Ach  = obuf + S;
    float* Bch  = Ach + Sc;
    float* Hin  = Bch + Sc;

    const size_t need = (3 * S + 3 * Sc) * sizeof(float);
    if (ws_size < need) {
        fprintf(stderr, "QRNN kernel: ws_size=%zu < needed %zu bytes!\n",
                ws_size, need);
    }

    dim3 g1(M_ / BM, 12);
    gemm_act_kernel<<<g1, 256, 0, stream>>>(x, Wz, bz, Wf, bf, Wo, bo,
                                            zbuf, fbuf, obuf);
    chunk_summary_kernel<<<dim3(B_ * NCH * 2), 256, 0, stream>>>(fbuf, zbuf, Ach, Bch);
    chunk_prefix_kernel<<<dim3(32), 256, 0, stream>>>(Ach, Bch, Hin);
    scan_apply_kernel<<<dim3(B_ * NCH * 2), 256, 0, stream>>>(fbuf, zbuf, obuf, Hin, out);
}

// Round 2
// 817.108 us; speedup vs baseline: 3.3409x; 3.3409x over previous
//
#include <hip/hip_runtime.h>
#include <cstdio>
#include <cstdint>

// Problem constants
#define B_  16
#define T_  4096
#define D_  512
#define U_  512
#define KK  1024            // W*D
#define M_  (B_*T_)         // 65536 rows
#define NTOT 1536           // 3 gates * U

// Scan chunking
#define CHUNK 128
#define NCH   (T_/CHUNK)    // 32 chunks per sequence

typedef __attribute__((ext_vector_type(8))) short  bf16x8;
typedef __attribute__((ext_vector_type(4))) float  f32x4;
typedef __attribute__((ext_vector_type(8))) unsigned short u16x8;

__device__ __forceinline__ unsigned short f2bf(float f) {
    unsigned int u = __float_as_uint(f);
    unsigned int r = (u + 0x7fffu + ((u >> 16) & 1u)) >> 16;   // RNE
    return (unsigned short)r;
}

__device__ __forceinline__ void gl_lds16(const void* g, void* l) {
    __builtin_amdgcn_global_load_lds(
        (const __attribute__((address_space(1))) void*)g,
        (__attribute__((address_space(3))) void*)l, 16, 0, 0);
}

// ---------------------------------------------------------------------------
// Convert x (fp32 [16][4096][512]) -> xz (bf16 [16][4097][512]) with a zero
// row at t=0 per batch (causal pad).  A-row for (b,t) is then the contiguous
// 1024-elem span starting at (b*4097 + t)*512.
// ---------------------------------------------------------------------------
__global__ __launch_bounds__(256)
void convert_x_kernel(const float* __restrict__ x, unsigned short* __restrict__ xz)
{
    const size_t e = ((size_t)blockIdx.x * 256 + threadIdx.x) * 8;
    const size_t row = e >> 9;                 // 0 .. 16*4097-1
    const int    d   = (int)(e & 511);
    const int    tz  = (int)(row % 4097);
    const size_t b   = row / 4097;
    u16x8 o;
    if (tz == 0) {
        #pragma unroll
        for (int i = 0; i < 8; ++i) o[i] = 0;
    } else {
        const size_t src = (((b << 12) + (size_t)(tz - 1)) << 9) + d;
        const float4 v0 = *reinterpret_cast<const float4*>(x + src);
        const float4 v1 = *reinterpret_cast<const float4*>(x + src + 4);
        o[0] = f2bf(v0.x); o[1] = f2bf(v0.y); o[2] = f2bf(v0.z); o[3] = f2bf(v0.w);
        o[4] = f2bf(v1.x); o[5] = f2bf(v1.y); o[6] = f2bf(v1.z); o[7] = f2bf(v1.w);
    }
    *reinterpret_cast<u16x8*>(xz + e) = o;
}

// ---------------------------------------------------------------------------
// Transpose + convert weights: Wt[(g*512+u)*1024 + k] = Wg[k*512 + u]  (bf16)
// grid (32, 16, 3), block (32, 8)
// ---------------------------------------------------------------------------
__global__ __launch_bounds__(256)
void convert_wt_kernel(const float* __restrict__ Wz, const float* __restrict__ Wf,
                       const float* __restrict__ Wo, unsigned short* __restrict__ Wt)
{
    __shared__ float tile[32][33];
    const int g = blockIdx.z;
    const float* __restrict__ W = (g == 0) ? Wz : (g == 1 ? Wf : Wo);
    const int k0 = blockIdx.x * 32;
    const int u0 = blockIdx.y * 32;
    const int tx = threadIdx.x, ty = threadIdx.y;
    #pragma unroll
    for (int r = 0; r < 4; ++r)
        tile[ty + r * 8][tx] = W[(size_t)(k0 + ty + r * 8) * 512 + u0 + tx];
    __syncthreads();
    #pragma unroll
    for (int r = 0; r < 4; ++r) {
        const int u = u0 + ty + r * 8;
        Wt[(size_t)(g * 512 + u) * 1024 + k0 + tx] = f2bf(tile[tx][ty + r * 8]);
    }
}

// ---------------------------------------------------------------------------
// bf16 MFMA GEMM + bias + activation.
// C[65536, 1536] = A[65536, 1024] x Wt^T ; A rows from xz (contiguous), Wt is
// N-major (gemm_bt).  128x128 tile, BK=64, global_load_lds(16B) staging with
// XOR chunk swizzle, 16x16x32 bf16 MFMA, 4 waves each computing 64x64.
// grid (512, 12): blockIdx.y -> gate = y>>2, u-quarter = y&3.
// ---------------------------------------------------------------------------
__global__ __launch_bounds__(256)
void gemm_mfma_kernel(const unsigned short* __restrict__ xz,
                      const unsigned short* __restrict__ Wt,
                      const float* __restrict__ bz, const float* __restrict__ bfg,
                      const float* __restrict__ bo,
                      float* __restrict__ zbuf, float* __restrict__ fbuf,
                      float* __restrict__ obuf)
{
    __shared__ unsigned short As[128 * 64];   // 16 KB
    __shared__ unsigned short Bs[128 * 64];   // 16 KB

    const int tid  = threadIdx.x;
    const int lane = tid & 63;
    const int wave = tid >> 6;
    const int wm   = wave >> 1;          // 0..1
    const int wn   = wave & 1;           // 0..1
    const int m0   = blockIdx.x * 128;
    const int nblk = blockIdx.y;         // 0..11
    const int n0   = nblk * 128;         // global col in [0,1536)

    // ---- staging address setup ----
    const int swz = (lane & 7) ^ (lane >> 3);      // swizzled 16B-chunk index
    const unsigned short* gA[4];
    const unsigned short* gB[4];
    #pragma unroll
    for (int i = 0; i < 4; ++i) {
        const int r = i * 32 + wave * 8 + (lane >> 3);
        const int m = m0 + r;
        const int b = m >> 12;
        const int t = m & 4095;
        gA[i] = xz + ((size_t)(b * 4097 + t) << 9) + swz * 8;
        gB[i] = Wt + ((size_t)(n0 + r) << 10) + swz * 8;
    }
    char* AsB = (char*)As;
    char* BsB = (char*)Bs;

    f32x4 acc[4][4];
    #pragma unroll
    for (int i = 0; i < 4; ++i)
        #pragma unroll
        for (int j = 0; j < 4; ++j)
            acc[i][j] = (f32x4){0.f, 0.f, 0.f, 0.f};

    // ---- K loop: 16 iterations of BK=64 ----
    for (int kk = 0; kk < 16; ++kk) {
        #pragma unroll
        for (int i = 0; i < 4; ++i)
            gl_lds16(gA[i] + kk * 64, AsB + i * 4096 + wave * 1024);
        #pragma unroll
        for (int i = 0; i < 4; ++i)
            gl_lds16(gB[i] + kk * 64, BsB + i * 4096 + wave * 1024);
        __syncthreads();

        #pragma unroll
        for (int ks = 0; ks < 2; ++ks) {
            const int ch = (ks * 4 + (lane >> 4)) ^ (lane & 7);
            bf16x8 av[4], bv[4];
            #pragma unroll
            for (int i = 0; i < 4; ++i) {
                const int row = wm * 64 + i * 16 + (lane & 15);
                av[i] = *reinterpret_cast<const bf16x8*>(AsB + row * 128 + ch * 16);
            }
            #pragma unroll
            for (int j = 0; j < 4; ++j) {
                const int row = wn * 64 + j * 16 + (lane & 15);
                bv[j] = *reinterpret_cast<const bf16x8*>(BsB + row * 128 + ch * 16);
            }
            #pragma unroll
            for (int i = 0; i < 4; ++i)
                #pragma unroll
                for (int j = 0; j < 4; ++j)
                    acc[i][j] = __builtin_amdgcn_mfma_f32_16x16x32_bf16(
                        av[i], bv[j], acc[i][j], 0, 0, 0);
        }
        __syncthreads();
    }

    // ---- epilogue: bias + activation + store ----
    const int gate = nblk >> 2;                      // uniform per block
    float* __restrict__ outg = (gate == 0) ? zbuf : (gate == 1 ? fbuf : obuf);
    const float* __restrict__ bg = (gate == 0) ? bz : (gate == 1 ? bfg : bo);
    const int ng0 = (nblk & 3) * 128 + wn * 64 + (lane & 15);   // col within gate
    const int mb  = m0 + wm * 64 + ((lane >> 4) << 2);

    #pragma unroll
    for (int j = 0; j < 4; ++j) {
        const int n = ng0 + j * 16;
        const float bias = bg[n];
        #pragma unroll
        for (int i = 0; i < 4; ++i) {
            const int mrow = mb + i * 16;
            #pragma unroll
            for (int r = 0; r < 4; ++r) {
                float v = acc[i][j][r] + bias;
                if (gate == 0)
                    v = 2.0f / (1.0f + __expf(-2.0f * v)) - 1.0f;   // tanh
                else
                    v = 1.0f / (1.0f + __expf(-v));                 // sigmoid
                outg[(size_t)(mrow + r) * 512 + n] = v;
            }
        }
    }
}

// ---------------------------------------------------------------------------
// Phase 1: per-chunk affine summary.
// ---------------------------------------------------------------------------
__global__ __launch_bounds__(256)
void chunk_summary_kernel(const float* __restrict__ fbuf,
                          const float* __restrict__ zbuf,
                          float* __restrict__ Ach, float* __restrict__ Bch)
{
    const int blk   = blockIdx.x;
    const int uhalf = blk & 1;
    const int bc    = blk >> 1;
    const int c     = bc & (NCH - 1);
    const int b     = bc >> 5;
    const int u     = uhalf * 256 + threadIdx.x;

    const long long base = ((long long)(b * T_ + c * CHUNK)) * U_ + u;
    float A = 1.0f, Bv = 0.0f;
    #pragma unroll 4
    for (int i = 0; i < CHUNK; ++i) {
        const float f = fbuf[base + (long long)i * U_];
        const float z = zbuf[base + (long long)i * U_];
        Bv = f * Bv + (1.0f - f) * z;
        A *= f;
    }
    const int idx = (b * NCH + c) * U_ + u;
    Ach[idx] = A;
    Bch[idx] = Bv;
}

// ---------------------------------------------------------------------------
// Phase 2: exclusive prefix over chunks per (b,u).
// ---------------------------------------------------------------------------
__global__ __launch_bounds__(256)
void chunk_prefix_kernel(const float* __restrict__ Ach,
                         const float* __restrict__ Bch,
                         float* __restrict__ Hin)
{
    const int g = blockIdx.x * 256 + threadIdx.x;   // 0..8191
    const int b = g >> 9;
    const int u = g & (U_ - 1);
    float h = 0.0f;
    #pragma unroll 4
    for (int c = 0; c < NCH; ++c) {
        const int idx = (b * NCH + c) * U_ + u;
        Hin[idx] = h;
        h = Ach[idx] * h + Bch[idx];
    }
}

// ---------------------------------------------------------------------------
// Phase 3: apply scan within chunk, multiply by o, write output.
// ---------------------------------------------------------------------------
__global__ __launch_bounds__(256)
void scan_apply_kernel(const float* __restrict__ fbuf,
                       const float* __restrict__ zbuf,
                       const float* __restrict__ obuf,
                       const float* __restrict__ Hin,
                       float* __restrict__ out)
{
    const int blk   = blockIdx.x;
    const int uhalf = blk & 1;
    const int bc    = blk >> 1;
    const int c     = bc & (NCH - 1);
    const int b     = bc >> 5;
    const int u     = uhalf * 256 + threadIdx.x;

    const long long base = ((long long)(b * T_ + c * CHUNK)) * U_ + u;
    float h = Hin[(b * NCH + c) * U_ + u];
    #pragma unroll 4
    for (int i = 0; i < CHUNK; ++i) {
        const long long p = base + (long long)i * U_;
        const float f = fbuf[p];
        const float z = zbuf[p];
        const float o = obuf[p];
        h = f * h + (1.0f - f) * z;
        out[p] = o * h;
    }
}

// ---------------------------------------------------------------------------
extern "C" void kernel_launch(void* const* d_in, const int* in_sizes, int n_in,
                              void* d_out, int out_size, void* d_ws, size_t ws_size,
                              hipStream_t stream)
{
    const float* x  = (const float*)d_in[0];
    const float* Wz = (const float*)d_in[1];
    const float* bz = (const float*)d_in[2];
    const float* Wf = (const float*)d_in[3];
    const float* bf = (const float*)d_in[4];
    const float* Wo = (const float*)d_in[5];
    const float* bo = (const float*)d_in[6];
    float* out = (float*)d_out;

    const size_t S  = (size_t)M_ * U_;            // 33,554,432 per gate buffer
    const size_t Sc = (size_t)B_ * NCH * U_;      // 262,144 per chunk buffer
    const size_t XZ = (size_t)B_ * (T_ + 1) * D_; // 33,562,624 bf16 elems
    const size_t WT = (size_t)NTOT * KK;          // 1,572,864 bf16 elems

    float* zbuf = (float*)d_ws;
    float* fbuf = zbuf + S;
    float* obuf = fbuf + S;
    unsigned short* xz = (unsigned short*)(obuf + S);
    unsigned short* Wt = xz + XZ;
    float* Ach = (float*)(Wt + WT);
    float* Bch = Ach + Sc;
    float* Hin = Bch + Sc;

    const size_t need = 3 * S * sizeof(float) + (XZ + WT) * sizeof(unsigned short)
                      + 3 * Sc * sizeof(float);
    if (ws_size < need) {
        fprintf(stderr, "QRNN kernel: ws_size=%zu < needed %zu bytes!\n",
                ws_size, need);
    }

    // 1. converts
    {
        const size_t nthreads = XZ / 8;                   // 4,195,328
        convert_x_kernel<<<dim3((unsigned)(nthreads / 256)), 256, 0, stream>>>(x, xz);
        convert_wt_kernel<<<dim3(32, 16, 3), dim3(32, 8), 0, stream>>>(Wz, Wf, Wo, Wt);
    }
    // 2. fused bf16 MFMA GEMM + activations
    gemm_mfma_kernel<<<dim3(M_ / 128, 12), 256, 0, stream>>>(
        xz, Wt, bz, bf, bo, zbuf, fbuf, obuf);
    // 3. scan
    chunk_summary_kernel<<<dim3(B_ * NCH * 2), 256, 0, stream>>>(fbuf, zbuf, Ach, Bch);
    chunk_prefix_kernel<<<dim3(32), 256, 0, stream>>>(Ach, Bch, Hin);
    scan_apply_kernel<<<dim3(B_ * NCH * 2), 256, 0, stream>>>(fbuf, zbuf, obuf, Hin, out);
}

// Round 3
// 735.956 us; speedup vs baseline: 3.7093x; 1.1103x over previous
//
#include <hip/hip_runtime.h>
#include <cstdio>
#include <cstdint>

// Problem constants
#define B_  16
#define T_  4096
#define D_  512
#define U_  512
#define KK  1024            // W*D
#define M_  (B_*T_)         // 65536 rows
#define NTOT 1536           // 3 gates * U

// Scan chunking
#define CHUNK 128
#define NCH   (T_/CHUNK)    // 32 chunks per sequence

typedef __attribute__((ext_vector_type(8))) short  bf16x8;
typedef __attribute__((ext_vector_type(4))) float  f32x4;
typedef __attribute__((ext_vector_type(8))) unsigned short u16x8;

__device__ __forceinline__ unsigned short f2bf(float f) {
    unsigned int u = __float_as_uint(f);
    unsigned int r = (u + 0x7fffu + ((u >> 16) & 1u)) >> 16;   // RNE
    return (unsigned short)r;
}

__device__ __forceinline__ void gl_lds16(const void* g, void* l) {
    __builtin_amdgcn_global_load_lds(
        (const __attribute__((address_space(1))) void*)g,
        (__attribute__((address_space(3))) void*)l, 16, 0, 0);
}

// ---------------------------------------------------------------------------
// Convert x (fp32 [16][4096][512]) -> xz (bf16 [16][4097][512]) with a zero
// row at t=0 per batch (causal pad).
// ---------------------------------------------------------------------------
__global__ __launch_bounds__(256)
void convert_x_kernel(const float* __restrict__ x, unsigned short* __restrict__ xz)
{
    const size_t e = ((size_t)blockIdx.x * 256 + threadIdx.x) * 8;
    const size_t row = e >> 9;                 // 0 .. 16*4097-1
    const int    d   = (int)(e & 511);
    const int    tz  = (int)(row % 4097);
    const size_t b   = row / 4097;
    u16x8 o;
    if (tz == 0) {
        #pragma unroll
        for (int i = 0; i < 8; ++i) o[i] = 0;
    } else {
        const size_t src = (((b << 12) + (size_t)(tz - 1)) << 9) + d;
        const float4 v0 = *reinterpret_cast<const float4*>(x + src);
        const float4 v1 = *reinterpret_cast<const float4*>(x + src + 4);
        o[0] = f2bf(v0.x); o[1] = f2bf(v0.y); o[2] = f2bf(v0.z); o[3] = f2bf(v0.w);
        o[4] = f2bf(v1.x); o[5] = f2bf(v1.y); o[6] = f2bf(v1.z); o[7] = f2bf(v1.w);
    }
    *reinterpret_cast<u16x8*>(xz + e) = o;
}

// ---------------------------------------------------------------------------
// Transpose + convert weights: Wt[(g*512+u)*1024 + k] = Wg[k*512 + u]  (bf16)
// ---------------------------------------------------------------------------
__global__ __launch_bounds__(256)
void convert_wt_kernel(const float* __restrict__ Wz, const float* __restrict__ Wf,
                       const float* __restrict__ Wo, unsigned short* __restrict__ Wt)
{
    __shared__ float tile[32][33];
    const int g = blockIdx.z;
    const float* __restrict__ W = (g == 0) ? Wz : (g == 1 ? Wf : Wo);
    const int k0 = blockIdx.x * 32;
    const int u0 = blockIdx.y * 32;
    const int tx = threadIdx.x, ty = threadIdx.y;
    #pragma unroll
    for (int r = 0; r < 4; ++r)
        tile[ty + r * 8][tx] = W[(size_t)(k0 + ty + r * 8) * 512 + u0 + tx];
    __syncthreads();
    #pragma unroll
    for (int r = 0; r < 4; ++r) {
        const int u = u0 + ty + r * 8;
        Wt[(size_t)(g * 512 + u) * 1024 + k0 + tx] = f2bf(tile[tx][ty + r * 8]);
    }
}

// ---------------------------------------------------------------------------
// bf16 MFMA GEMM + bias + activation.
// grid (12, 512): blockIdx.x = nblk (FASTEST) so the 12 blocks sharing one
// A m-tile dispatch adjacently -> A fetched from HBM once, re-read from L3.
// ---------------------------------------------------------------------------
__global__ __launch_bounds__(256)
void gemm_mfma_kernel(const unsigned short* __restrict__ xz,
                      const unsigned short* __restrict__ Wt,
                      const float* __restrict__ bz, const float* __restrict__ bfg,
                      const float* __restrict__ bo,
                      float* __restrict__ zbuf, float* __restrict__ fbuf,
                      float* __restrict__ obuf)
{
    __shared__ unsigned short As[128 * 64];   // 16 KB
    __shared__ unsigned short Bs[128 * 64];   // 16 KB

    const int tid  = threadIdx.x;
    const int lane = tid & 63;
    const int wave = tid >> 6;
    const int wm   = wave >> 1;          // 0..1
    const int wn   = wave & 1;           // 0..1
    const int nblk = blockIdx.x;         // 0..11  (fastest-varying)
    const int m0   = blockIdx.y * 128;
    const int n0   = nblk * 128;         // global col in [0,1536)

    // ---- staging address setup ----
    const int swz = (lane & 7) ^ (lane >> 3);      // swizzled 16B-chunk index
    const unsigned short* gA[4];
    const unsigned short* gB[4];
    #pragma unroll
    for (int i = 0; i < 4; ++i) {
        const int r = i * 32 + wave * 8 + (lane >> 3);
        const int m = m0 + r;
        const int b = m >> 12;
        const int t = m & 4095;
        gA[i] = xz + ((size_t)(b * 4097 + t) << 9) + swz * 8;
        gB[i] = Wt + ((size_t)(n0 + r) << 10) + swz * 8;
    }
    char* AsB = (char*)As;
    char* BsB = (char*)Bs;

    f32x4 acc[4][4];
    #pragma unroll
    for (int i = 0; i < 4; ++i)
        #pragma unroll
        for (int j = 0; j < 4; ++j)
            acc[i][j] = (f32x4){0.f, 0.f, 0.f, 0.f};

    // ---- K loop: 16 iterations of BK=64 ----
    for (int kk = 0; kk < 16; ++kk) {
        #pragma unroll
        for (int i = 0; i < 4; ++i)
            gl_lds16(gA[i] + kk * 64, AsB + i * 4096 + wave * 1024);
        #pragma unroll
        for (int i = 0; i < 4; ++i)
            gl_lds16(gB[i] + kk * 64, BsB + i * 4096 + wave * 1024);
        __syncthreads();

        #pragma unroll
        for (int ks = 0; ks < 2; ++ks) {
            const int ch = (ks * 4 + (lane >> 4)) ^ (lane & 7);
            bf16x8 av[4], bv[4];
            #pragma unroll
            for (int i = 0; i < 4; ++i) {
                const int row = wm * 64 + i * 16 + (lane & 15);
                av[i] = *reinterpret_cast<const bf16x8*>(AsB + row * 128 + ch * 16);
            }
            #pragma unroll
            for (int j = 0; j < 4; ++j) {
                const int row = wn * 64 + j * 16 + (lane & 15);
                bv[j] = *reinterpret_cast<const bf16x8*>(BsB + row * 128 + ch * 16);
            }
            #pragma unroll
            for (int i = 0; i < 4; ++i)
                #pragma unroll
                for (int j = 0; j < 4; ++j)
                    acc[i][j] = __builtin_amdgcn_mfma_f32_16x16x32_bf16(
                        av[i], bv[j], acc[i][j], 0, 0, 0);
        }
        __syncthreads();
    }

    // ---- epilogue: bias + activation + store ----
    const int gate = nblk >> 2;                      // uniform per block
    float* __restrict__ outg = (gate == 0) ? zbuf : (gate == 1 ? fbuf : obuf);
    const float* __restrict__ bg = (gate == 0) ? bz : (gate == 1 ? bfg : bo);
    const int ng0 = (nblk & 3) * 128 + wn * 64 + (lane & 15);   // col within gate
    const int mb  = m0 + wm * 64 + ((lane >> 4) << 2);

    #pragma unroll
    for (int j = 0; j < 4; ++j) {
        const int n = ng0 + j * 16;
        const float bias = bg[n];
        #pragma unroll
        for (int i = 0; i < 4; ++i) {
            const int mrow = mb + i * 16;
            #pragma unroll
            for (int r = 0; r < 4; ++r) {
                float v = acc[i][j][r] + bias;
                if (gate == 0)
                    v = 2.0f / (1.0f + __expf(-2.0f * v)) - 1.0f;   // tanh
                else
                    v = 1.0f / (1.0f + __expf(-v));                 // sigmoid
                outg[(size_t)(mrow + r) * 512 + n] = v;
            }
        }
    }
}

// ---------------------------------------------------------------------------
// Phase 1: per-chunk affine summary.  One block per (b, chunk); each thread
// handles 2 consecutive u via float2 (2 KB contiguous per wave-row).
// ---------------------------------------------------------------------------
__global__ __launch_bounds__(256)
void chunk_summary_kernel(const float* __restrict__ fbuf,
                          const float* __restrict__ zbuf,
                          float* __restrict__ Ach, float* __restrict__ Bch)
{
    const int bc = blockIdx.x;           // 0..511
    const int c  = bc & (NCH - 1);
    const int b  = bc >> 5;              // NCH = 32
    const int u  = threadIdx.x * 2;

    const long long base = ((long long)(b * T_ + c * CHUNK)) * U_ + u;
    float2 A = make_float2(1.0f, 1.0f);
    float2 Bv = make_float2(0.0f, 0.0f);
    #pragma unroll 8
    for (int i = 0; i < CHUNK; ++i) {
        const float2 f = *reinterpret_cast<const float2*>(fbuf + base + (long long)i * U_);
        const float2 z = *reinterpret_cast<const float2*>(zbuf + base + (long long)i * U_);
        Bv.x = f.x * Bv.x + (1.0f - f.x) * z.x;
        Bv.y = f.y * Bv.y + (1.0f - f.y) * z.y;
        A.x *= f.x;
        A.y *= f.y;
    }
    const int idx = (b * NCH + c) * U_ + u;
    *reinterpret_cast<float2*>(Ach + idx) = A;
    *reinterpret_cast<float2*>(Bch + idx) = Bv;
}

// ---------------------------------------------------------------------------
// Phase 2: exclusive prefix over chunks per (b,u). float2 per thread.
// grid: 16 blocks x 256 threads = 4096 threads x 2 u = 8192 (b,u) pairs.
// ---------------------------------------------------------------------------
__global__ __launch_bounds__(256)
void chunk_prefix_kernel(const float* __restrict__ Ach,
                         const float* __restrict__ Bch,
                         float* __restrict__ Hin)
{
    const int g = blockIdx.x * 256 + threadIdx.x;   // 0..4095
    const int b = g >> 8;
    const int u = (g & 255) * 2;
    float2 h = make_float2(0.0f, 0.0f);
    #pragma unroll 4
    for (int c = 0; c < NCH; ++c) {
        const int idx = (b * NCH + c) * U_ + u;
        *reinterpret_cast<float2*>(Hin + idx) = h;
        const float2 A = *reinterpret_cast<const float2*>(Ach + idx);
        const float2 Bv = *reinterpret_cast<const float2*>(Bch + idx);
        h.x = A.x * h.x + Bv.x;
        h.y = A.y * h.y + Bv.y;
    }
}

// ---------------------------------------------------------------------------
// Phase 3: apply scan within chunk, multiply by o, write output. float2.
// ---------------------------------------------------------------------------
__global__ __launch_bounds__(256)
void scan_apply_kernel(const float* __restrict__ fbuf,
                       const float* __restrict__ zbuf,
                       const float* __restrict__ obuf,
                       const float* __restrict__ Hin,
                       float* __restrict__ out)
{
    const int bc = blockIdx.x;           // 0..511
    const int c  = bc & (NCH - 1);
    const int b  = bc >> 5;
    const int u  = threadIdx.x * 2;

    const long long base = ((long long)(b * T_ + c * CHUNK)) * U_ + u;
    float2 h = *reinterpret_cast<const float2*>(Hin + (b * NCH + c) * U_ + u);
    #pragma unroll 8
    for (int i = 0; i < CHUNK; ++i) {
        const long long p = base + (long long)i * U_;
        const float2 f = *reinterpret_cast<const float2*>(fbuf + p);
        const float2 z = *reinterpret_cast<const float2*>(zbuf + p);
        const float2 o = *reinterpret_cast<const float2*>(obuf + p);
        h.x = f.x * h.x + (1.0f - f.x) * z.x;
        h.y = f.y * h.y + (1.0f - f.y) * z.y;
        float2 r;
        r.x = o.x * h.x;
        r.y = o.y * h.y;
        *reinterpret_cast<float2*>(out + p) = r;
    }
}

// ---------------------------------------------------------------------------
extern "C" void kernel_launch(void* const* d_in, const int* in_sizes, int n_in,
                              void* d_out, int out_size, void* d_ws, size_t ws_size,
                              hipStream_t stream)
{
    const float* x  = (const float*)d_in[0];
    const float* Wz = (const float*)d_in[1];
    const float* bz = (const float*)d_in[2];
    const float* Wf = (const float*)d_in[3];
    const float* bf = (const float*)d_in[4];
    const float* Wo = (const float*)d_in[5];
    const float* bo = (const float*)d_in[6];
    float* out = (float*)d_out;

    const size_t S  = (size_t)M_ * U_;            // 33,554,432 per gate buffer
    const size_t Sc = (size_t)B_ * NCH * U_;      // 262,144 per chunk buffer
    const size_t XZ = (size_t)B_ * (T_ + 1) * D_; // 33,562,624 bf16 elems
    const size_t WT = (size_t)NTOT * KK;          // 1,572,864 bf16 elems

    float* zbuf = (float*)d_ws;
    float* fbuf = zbuf + S;
    float* obuf = fbuf + S;
    unsigned short* xz = (unsigned short*)(obuf + S);
    unsigned short* Wt = xz + XZ;
    float* Ach = (float*)(Wt + WT);
    float* Bch = Ach + Sc;
    float* Hin = Bch + Sc;

    const size_t need = 3 * S * sizeof(float) + (XZ + WT) * sizeof(unsigned short)
                      + 3 * Sc * sizeof(float);
    if (ws_size < need) {
        fprintf(stderr, "QRNN kernel: ws_size=%zu < needed %zu bytes!\n",
                ws_size, need);
    }

    // 1. converts
    {
        const size_t nthreads = XZ / 8;                   // 4,195,328
        convert_x_kernel<<<dim3((unsigned)(nthreads / 256)), 256, 0, stream>>>(x, xz);
        convert_wt_kernel<<<dim3(32, 16, 3), dim3(32, 8), 0, stream>>>(Wz, Wf, Wo, Wt);
    }
    // 2. fused bf16 MFMA GEMM + activations (nblk fastest for A-tile L3 reuse)
    gemm_mfma_kernel<<<dim3(12, M_ / 128), 256, 0, stream>>>(
        xz, Wt, bz, bf, bo, zbuf, fbuf, obuf);
    // 3. scan
    chunk_summary_kernel<<<dim3(B_ * NCH), 256, 0, stream>>>(fbuf, zbuf, Ach, Bch);
    chunk_prefix_kernel<<<dim3(16), 256, 0, stream>>>(Ach, Bch, Hin);
    scan_apply_kernel<<<dim3(B_ * NCH), 256, 0, stream>>>(fbuf, zbuf, obuf, Hin, out);
}